// Round 3
// baseline (1531.941 us; speedup 1.0000x reference)
//
#include <hip/hip_runtime.h>
#include <math.h>

#define B_ 16
#define L_ 1024
#define M_TOT (B_*L_)   // 16384

__device__ __forceinline__ float wave_reduce_sum(float v) {
#pragma unroll
  for (int o = 32; o >= 1; o >>= 1) v += __shfl_xor(v, o, 64);
  return v;
}

// ---------------- featurize: z (B,L,64), boundary (B,L) ----------------
__global__ __launch_bounds__(64) void featurize_kernel(
    const float* __restrict__ pts, const float* __restrict__ fs, const float* __restrict__ ft,
    const float* __restrict__ w_space, const float* __restrict__ b_space,
    const float* __restrict__ w_time, const float* __restrict__ b_time,
    const float* __restrict__ w_fout, const float* __restrict__ b_fout,
    const float* __restrict__ w_gate, const float* __restrict__ b_gate,
    float* __restrict__ z, int* __restrict__ boundary)
{
  const int p = blockIdx.x;
  const int d = threadIdx.x;
  const float TWO_PI = 6.283185307179586f;
  __shared__ float feat[32];
  __shared__ float tfeat[16];
  __shared__ float g96[96];
  const float x = pts[p*3+0], y = pts[p*3+1], t = pts[p*3+2];
  if (d < 16) {
    float sp = (x*fs[d] + y*fs[16+d]) * TWO_PI;
    feat[d]    = sinf(sp);
    feat[16+d] = cosf(sp);
  } else if (d < 24) {
    int r = d - 16;
    float tp = t * ft[r] * TWO_PI;
    tfeat[r]   = sinf(tp);
    tfeat[8+r] = cosf(tp);
  }
  __syncthreads();
  float sf = b_space[d];
#pragma unroll
  for (int k2 = 0; k2 < 32; ++k2) sf = fmaf(feat[k2], w_space[k2*64+d], sf);
  g96[d] = sf;
  if (d < 32) {
    float tf = b_time[d];
#pragma unroll
    for (int k2 = 0; k2 < 16; ++k2) tf = fmaf(tfeat[k2], w_time[k2*32+d], tf);
    g96[64+d] = tf;
  }
  __syncthreads();
  float zv = b_fout[d];
#pragma unroll
  for (int k2 = 0; k2 < 96; ++k2) zv = fmaf(g96[k2], w_fout[k2*64+d], zv);
  z[(size_t)p*64+d] = zv;
  float gv = wave_reduce_sum(zv * w_gate[d]);
  if (d == 0) {
    float logit = gv + b_gate[0];
    float gate = 1.0f / (1.0f + expf(-logit));
    int bnd = (gate > 0.5f) ? 1 : 0;
    if ((p & (L_-1)) == 0) bnd = 1;
    boundary[p] = bnd;
  }
}

// ---------------- scan: seg_id, seg_start, n_seg ----------------
__global__ __launch_bounds__(1024) void scan_kernel(const int* __restrict__ boundary,
    int* __restrict__ seg_id, int* __restrict__ seg_start, int* __restrict__ n_seg)
{
  __shared__ int sc[1024];
  const int b = blockIdx.x, l = threadIdx.x;
  const int v = boundary[b*L_ + l];
  sc[l] = v;
  __syncthreads();
  for (int off = 1; off < 1024; off <<= 1) {
    int add = (l >= off) ? sc[l - off] : 0;
    __syncthreads();
    sc[l] += add;
    __syncthreads();
  }
  const int sid = sc[l] - 1;
  seg_id[b*L_ + l] = sid;
  if (v) seg_start[b*(L_+1) + sid] = l;
  if (l == L_-1) {
    n_seg[b] = sid + 1;
    seg_start[b*(L_+1) + sid + 1] = L_;
  }
}

// ---------------- generic GEMM: C = act(A[M,K] @ W[K,N] + bias) ----------------
template<int N, int K, bool RELU, bool GATED>
__global__ __launch_bounds__(256) void gemm_kernel(
    const float* __restrict__ A, const float* __restrict__ W,
    const float* __restrict__ bias, float* __restrict__ C,
    const int* __restrict__ nseg)
{
  constexpr int BM = 64, BK = 32;
  constexpr int TN = N / 16;
  const int row0 = blockIdx.x * BM;
  if (GATED) {
    const int b = row0 >> 10, i0 = row0 & (L_-1);
    if (i0 >= nseg[b]) return;
  }
  __shared__ float As[BM][BK + 4];
  const int tid = threadIdx.x;
  const int ty = tid >> 4, tx = tid & 15;
  float acc[4][TN];
#pragma unroll
  for (int i = 0; i < 4; ++i)
#pragma unroll
    for (int j = 0; j < TN; ++j) acc[i][j] = 0.f;
  const int lr = tid >> 2;
  const int lc = (tid & 3) * 8;
  for (int k0 = 0; k0 < K; k0 += BK) {
    const float4* src = reinterpret_cast<const float4*>(A + (size_t)(row0 + lr)*K + k0 + lc);
    float4 a0 = src[0], a1 = src[1];
    *reinterpret_cast<float4*>(&As[lr][lc])   = a0;
    *reinterpret_cast<float4*>(&As[lr][lc+4]) = a1;
    __syncthreads();
#pragma unroll 8
    for (int kk = 0; kk < BK; ++kk) {
      float a[4];
#pragma unroll
      for (int i = 0; i < 4; ++i) a[i] = As[ty*4+i][kk];
      const float4* wr = reinterpret_cast<const float4*>(W + (size_t)(k0+kk)*N + tx*TN);
      float w[TN];
#pragma unroll
      for (int j4 = 0; j4 < TN/4; ++j4) {
        float4 wv = wr[j4];
        w[j4*4+0]=wv.x; w[j4*4+1]=wv.y; w[j4*4+2]=wv.z; w[j4*4+3]=wv.w;
      }
#pragma unroll
      for (int i = 0; i < 4; ++i)
#pragma unroll
        for (int j = 0; j < TN; ++j)
          acc[i][j] = fmaf(a[i], w[j], acc[i][j]);
    }
    __syncthreads();
  }
#pragma unroll
  for (int i = 0; i < 4; ++i) {
    const int row = row0 + ty*4 + i;
#pragma unroll
    for (int j = 0; j < TN; ++j) {
      const int col = tx*TN + j;
      float v2 = acc[i][j] + bias[col];
      if (RELU) v2 = fmaxf(v2, 0.f);
      C[(size_t)row*N + col] = v2;
    }
  }
}

// ---------------- segment attention (block-diagonal, exact; fixed-shift softmax) --
__global__ __launch_bounds__(256) void seg_attn_kernel(
    const float* __restrict__ q, const float* __restrict__ k, const float* __restrict__ v,
    const int* __restrict__ seg_id, const int* __restrict__ seg_start,
    float* __restrict__ ao)
{
  const int idx = blockIdx.x * 256 + threadIdx.x;  // ((b*L + pt)*2 + h)
  const int h  = idx & 1;
  const int pt = (idx >> 1) & (L_-1);
  const int b  = idx >> 11;
  const float scale = 0.17677669529663687f; // 1/sqrt(32)
  const size_t rowq = (size_t)(b*L_ + pt)*64 + h*32;
  float qv[32];
  {
    const float4* qp = reinterpret_cast<const float4*>(q + rowq);
#pragma unroll
    for (int j4 = 0; j4 < 8; ++j4) {
      float4 t4 = qp[j4];
      qv[j4*4+0]=t4.x; qv[j4*4+1]=t4.y; qv[j4*4+2]=t4.z; qv[j4*4+3]=t4.w;
    }
  }
  const int s  = seg_id[b*L_ + pt];
  const int j0 = seg_start[b*(L_+1) + s];
  const int j1 = seg_start[b*(L_+1) + s + 1];
  float lsum = 0.f;
  float acc[32];
#pragma unroll
  for (int d = 0; d < 32; ++d) acc[d] = 0.f;
  for (int j = j0; j < j1; ++j) {
    const size_t rk = (size_t)(b*L_ + j)*64 + h*32;
    const float4* kp = reinterpret_cast<const float4*>(k + rk);
    float dot = 0.f;
#pragma unroll
    for (int j4 = 0; j4 < 8; ++j4) {
      float4 t4 = kp[j4];
      dot = fmaf(qv[j4*4+0], t4.x, dot);
      dot = fmaf(qv[j4*4+1], t4.y, dot);
      dot = fmaf(qv[j4*4+2], t4.z, dot);
      dot = fmaf(qv[j4*4+3], t4.w, dot);
    }
    // scores are tiny (|s| << 1): softmax with fixed shift 0 is exact (shift-invariant)
    const float p = __expf(fminf(dot * scale, 30.f));
    lsum += p;
    const float4* vp = reinterpret_cast<const float4*>(v + rk);
#pragma unroll
    for (int j4 = 0; j4 < 8; ++j4) {
      float4 t4 = vp[j4];
      acc[j4*4+0] = fmaf(p, t4.x, acc[j4*4+0]);
      acc[j4*4+1] = fmaf(p, t4.y, acc[j4*4+1]);
      acc[j4*4+2] = fmaf(p, t4.z, acc[j4*4+2]);
      acc[j4*4+3] = fmaf(p, t4.w, acc[j4*4+3]);
    }
  }
  const float inv = 1.0f / lsum;
  float* op = ao + rowq;
#pragma unroll
  for (int d = 0; d < 32; ++d) op[d] = acc[d] * inv;
}

// ---------------- global attention v3: NQ=2 per thread, key-split kt=2 ----------
// grid: blockIdx.x = (((b*4 + h)*4 + qt)*2 + kt); block = 128 threads (2 waves)
// Partial (unnormalized) sums written to part_acc/part_lsum; merged by glb_merge.
__global__ __launch_bounds__(128) void glb_attn_kernel(
    const float* __restrict__ q, const float* __restrict__ k, const float* __restrict__ v,
    const int* __restrict__ n_seg,
    float* __restrict__ part_acc, float* __restrict__ part_lsum)
{
  const int kt = blockIdx.x & 1;
  const int qt = (blockIdx.x >> 1) & 3;
  const int h  = (blockIdx.x >> 3) & 3;
  const int b  = blockIdx.x >> 5;
  const int ns = n_seg[b];
  if (qt*256 >= ns) return;
  const int kchunk = (ns + 1) >> 1;
  const int kbeg = kt * kchunk;
  const int kend = min(ns, kbeg + kchunk);
  if (kbeg >= kend) return;

  const int tid = (int)threadIdx.x;
  const int q0 = qt*256 + tid;
  const int q1 = q0 + 128;
  const bool a0 = q0 < ns, a1 = q1 < ns;
  const float scale = 0.17677669529663687f; // 1/sqrt(32)

  __shared__ float Ks[64][36];  // +4 pad: conflict-free staging writes, float4-aligned
  __shared__ float Vs[64][36];

  float qv0[32], qv1[32];
#pragma unroll
  for (int d = 0; d < 32; ++d) { qv0[d] = 0.f; qv1[d] = 0.f; }
  if (a0) {
    const float4* qp = reinterpret_cast<const float4*>(q + (size_t)(b*L_+q0)*128 + h*32);
#pragma unroll
    for (int j4 = 0; j4 < 8; ++j4) {
      float4 t4 = qp[j4];
      qv0[j4*4+0]=t4.x*scale; qv0[j4*4+1]=t4.y*scale; qv0[j4*4+2]=t4.z*scale; qv0[j4*4+3]=t4.w*scale;
    }
  }
  if (a1) {
    const float4* qp = reinterpret_cast<const float4*>(q + (size_t)(b*L_+q1)*128 + h*32);
#pragma unroll
    for (int j4 = 0; j4 < 8; ++j4) {
      float4 t4 = qp[j4];
      qv1[j4*4+0]=t4.x*scale; qv1[j4*4+1]=t4.y*scale; qv1[j4*4+2]=t4.z*scale; qv1[j4*4+3]=t4.w*scale;
    }
  }

  float l0 = 0.f, l1 = 0.f;
  float acc0[32], acc1[32];
#pragma unroll
  for (int d = 0; d < 32; ++d) { acc0[d] = 0.f; acc1[d] = 0.f; }

  for (int j0 = kbeg; j0 < kend; j0 += 64) {
    const int nj = min(64, kend - j0);
    __syncthreads();
    {
      const int jr = tid >> 1;
      const int c0 = (tid & 1) * 16;
      if (jr < nj) {
        const size_t base = (size_t)(b*L_ + j0 + jr)*128 + h*32 + c0;
        const float4* ksrc = reinterpret_cast<const float4*>(k + base);
        const float4* vsrc = reinterpret_cast<const float4*>(v + base);
        float4* kd = reinterpret_cast<float4*>(&Ks[jr][c0]);
        float4* vd = reinterpret_cast<float4*>(&Vs[jr][c0]);
        kd[0]=ksrc[0]; kd[1]=ksrc[1]; kd[2]=ksrc[2]; kd[3]=ksrc[3];
        vd[0]=vsrc[0]; vd[1]=vsrc[1]; vd[2]=vsrc[2]; vd[3]=vsrc[3];
      }
    }
    __syncthreads();
#pragma unroll 2
    for (int j = 0; j < nj; ++j) {
      const float4* kr = reinterpret_cast<const float4*>(&Ks[j][0]);
      float s0a=0.f,s0b=0.f,s1a=0.f,s1b=0.f;
#pragma unroll
      for (int j4 = 0; j4 < 8; ++j4) {
        float4 t4 = kr[j4];
        s0a = fmaf(qv0[j4*4+0], t4.x, s0a);
        s0b = fmaf(qv0[j4*4+1], t4.y, s0b);
        s0a = fmaf(qv0[j4*4+2], t4.z, s0a);
        s0b = fmaf(qv0[j4*4+3], t4.w, s0b);
        s1a = fmaf(qv1[j4*4+0], t4.x, s1a);
        s1b = fmaf(qv1[j4*4+1], t4.y, s1b);
        s1a = fmaf(qv1[j4*4+2], t4.z, s1a);
        s1b = fmaf(qv1[j4*4+3], t4.w, s1b);
      }
      // fixed-shift softmax: scores are O(0.3); clamp is pure overflow insurance
      const float p0 = __expf(fminf(s0a + s0b, 30.f));
      const float p1 = __expf(fminf(s1a + s1b, 30.f));
      l0 += p0; l1 += p1;
      const float4* vr = reinterpret_cast<const float4*>(&Vs[j][0]);
#pragma unroll
      for (int j4 = 0; j4 < 8; ++j4) {
        float4 t4 = vr[j4];
        acc0[j4*4+0] = fmaf(p0, t4.x, acc0[j4*4+0]);
        acc0[j4*4+1] = fmaf(p0, t4.y, acc0[j4*4+1]);
        acc0[j4*4+2] = fmaf(p0, t4.z, acc0[j4*4+2]);
        acc0[j4*4+3] = fmaf(p0, t4.w, acc0[j4*4+3]);
        acc1[j4*4+0] = fmaf(p1, t4.x, acc1[j4*4+0]);
        acc1[j4*4+1] = fmaf(p1, t4.y, acc1[j4*4+1]);
        acc1[j4*4+2] = fmaf(p1, t4.z, acc1[j4*4+2]);
        acc1[j4*4+3] = fmaf(p1, t4.w, acc1[j4*4+3]);
      }
    }
  }
  const int pb = ((b*4 + h)*2 + kt)*1024;
  if (a0) {
    part_lsum[pb + q0] = l0;
    float* pa = part_acc + (size_t)(pb + q0)*32;
#pragma unroll
    for (int j4 = 0; j4 < 8; ++j4)
      reinterpret_cast<float4*>(pa)[j4] = make_float4(acc0[j4*4+0],acc0[j4*4+1],acc0[j4*4+2],acc0[j4*4+3]);
  }
  if (a1) {
    part_lsum[pb + q1] = l1;
    float* pa = part_acc + (size_t)(pb + q1)*32;
#pragma unroll
    for (int j4 = 0; j4 < 8; ++j4)
      reinterpret_cast<float4*>(pa)[j4] = make_float4(acc1[j4*4+0],acc1[j4*4+1],acc1[j4*4+2],acc1[j4*4+3]);
  }
}

// ---------------- merge kt partials -> normalized attention output ----------------
// grid: blockIdx.x = ((b*4 + h)*16 + qt64); block = 256 (64 q x 4 d-groups of 8)
__global__ __launch_bounds__(256) void glb_merge_kernel(
    const float* __restrict__ part_acc, const float* __restrict__ part_lsum,
    const int* __restrict__ n_seg, float* __restrict__ ao)
{
  const int qt = blockIdx.x & 15;
  const int h  = (blockIdx.x >> 4) & 3;
  const int b  = blockIdx.x >> 6;
  const int ns = n_seg[b];
  const int q  = qt*64 + ((int)threadIdx.x >> 2);
  if (q >= ns) return;
  const int dg = ((int)threadIdx.x & 3) * 8;
  const int kchunk = (ns + 1) >> 1;
  float ls = 0.f;
  float a[8];
#pragma unroll
  for (int i = 0; i < 8; ++i) a[i] = 0.f;
#pragma unroll
  for (int kt = 0; kt < 2; ++kt) {
    if (kt * kchunk < ns) {
      const int base = ((b*4 + h)*2 + kt)*1024 + q;
      ls += part_lsum[base];
      const float4* pa = reinterpret_cast<const float4*>(part_acc + (size_t)base*32 + dg);
      float4 x0 = pa[0], x1 = pa[1];
      a[0]+=x0.x; a[1]+=x0.y; a[2]+=x0.z; a[3]+=x0.w;
      a[4]+=x1.x; a[5]+=x1.y; a[6]+=x1.z; a[7]+=x1.w;
    }
  }
  const float inv = 1.0f / ls;
  float* op = ao + (size_t)(b*L_ + q)*128 + h*32 + dg;
  reinterpret_cast<float4*>(op)[0] = make_float4(a[0]*inv, a[1]*inv, a[2]*inv, a[3]*inv);
  reinterpret_cast<float4*>(op)[1] = make_float4(a[4]*inv, a[5]*inv, a[6]*inv, a[7]*inv);
}

// ---------------- LN(x + r)*g + b, in place into x ----------------
template<int D, bool GATED>
__global__ __launch_bounds__(D) void ln_res_kernel(
    float* __restrict__ x, const float* __restrict__ r,
    const float* __restrict__ gam, const float* __restrict__ bet,
    const int* __restrict__ nseg)
{
  const size_t row = blockIdx.x;
  if (GATED) {
    const int b = (int)(row >> 10), i = (int)(row & (L_-1));
    if (i >= nseg[b]) return;
  }
  const int d = threadIdx.x;
  float val = x[row*D + d] + r[row*D + d];
  float s = wave_reduce_sum(val);
  __shared__ float red[4];
  if constexpr (D == 128) {
    if ((d & 63) == 0) red[d >> 6] = s;
    __syncthreads();
    s = red[0] + red[1];
  }
  const float mean = s / (float)D;
  const float dv = val - mean;
  float s2 = wave_reduce_sum(dv*dv);
  if constexpr (D == 128) {
    if ((d & 63) == 0) red[2 + (d >> 6)] = s2;
    __syncthreads();
    s2 = red[2] + red[3];
  }
  x[row*D + d] = dv * rsqrtf(s2 / (float)D + 1e-5f) * gam[d] + bet[d];
}

// ---------------- segment mean pooling ----------------
__global__ __launch_bounds__(64) void pool_kernel(
    const float* __restrict__ h, const int* __restrict__ seg_start,
    const int* __restrict__ n_seg, float* __restrict__ mean)
{
  const int b = blockIdx.x >> 10;
  const int s = blockIdx.x & (L_-1);
  if (s >= n_seg[b]) return;
  const int d = threadIdx.x;
  const int j0 = seg_start[b*(L_+1)+s], j1 = seg_start[b*(L_+1)+s+1];
  float acc = 0.f;
  for (int j = j0; j < j1; ++j) acc += h[(size_t)(b*L_+j)*64 + d];
  mean[(size_t)(b*L_+s)*64 + d] = acc / (float)(j1 - j0);
}

// ---------------- final: pooled @ fin_w + fin_b ----------------
__global__ __launch_bounds__(128) void final_kernel(
    const float* __restrict__ g, const float* __restrict__ semb,
    const int* __restrict__ n_seg, const float* __restrict__ fin_w,
    const float* __restrict__ fin_b, float* __restrict__ out)
{
  const int b = blockIdx.x, d = threadIdx.x;
  const int ns = n_seg[b];
  __shared__ float pl[128];
  float pooled;
  if (ns == 1) pooled = semb[(size_t)(b*L_)*128 + d];
  else {
    float acc = 0.f;
    for (int i = 0; i < ns; ++i) acc += g[(size_t)(b*L_+i)*128 + d];
    pooled = acc / (float)ns;
  }
  pl[d] = pooled;
  __syncthreads();
  float o = fin_b[d];
#pragma unroll 8
  for (int k2 = 0; k2 < 128; ++k2) o = fmaf(pl[k2], fin_w[k2*128+d], o);
  out[b*128+d] = o;
}

extern "C" void kernel_launch(void* const* d_in, const int* in_sizes, int n_in,
                              void* d_out, int out_size, void* d_ws, size_t ws_size,
                              hipStream_t stream) {
  const float* pts     = (const float*)d_in[0];
  const float* fs      = (const float*)d_in[1];
  const float* ft      = (const float*)d_in[2];
  const float* w_space = (const float*)d_in[3];
  const float* b_space = (const float*)d_in[4];
  const float* w_time  = (const float*)d_in[5];
  const float* b_time  = (const float*)d_in[6];
  const float* w_fout  = (const float*)d_in[7];
  const float* b_fout  = (const float*)d_in[8];
  const float* w_gate  = (const float*)d_in[9];
  const float* b_gate  = (const float*)d_in[10];
  const float* seg_attn_w = (const float*)d_in[11];
  const float* seg_attn_b = (const float*)d_in[12];
  const float* seg_ln_g   = (const float*)d_in[13];
  const float* seg_ln_b   = (const float*)d_in[14];
  const float* seg_ff1_w  = (const float*)d_in[15];
  const float* seg_ff1_b  = (const float*)d_in[16];
  const float* seg_ff2_w  = (const float*)d_in[17];
  const float* seg_ff2_b  = (const float*)d_in[18];
  const float* glb_attn_w = (const float*)d_in[19];
  const float* glb_attn_b = (const float*)d_in[20];
  const float* glb_ln_g   = (const float*)d_in[21];
  const float* glb_ln_b   = (const float*)d_in[22];
  const float* glb_ff1_w  = (const float*)d_in[23];
  const float* glb_ff1_b  = (const float*)d_in[24];
  const float* glb_ff2_w  = (const float*)d_in[25];
  const float* glb_ff2_b  = (const float*)d_in[26];
  const float* up_w    = (const float*)d_in[27];
  const float* up_b    = (const float*)d_in[28];
  const float* fin_w   = (const float*)d_in[29];
  const float* fin_b   = (const float*)d_in[30];

  char* ws = (char*)d_ws;
  float* zx   = (float*)(ws);                         // 16384*64  = 4MB
  float* qb   = (float*)(ws + ((size_t)4  << 20));    // 8MB
  float* kb   = (float*)(ws + ((size_t)12 << 20));    // 8MB
  float* vb   = (float*)(ws + ((size_t)20 << 20));    // 8MB
  float* aob  = (float*)(ws + ((size_t)28 << 20));    // 8MB
  float* xg   = (float*)(ws + ((size_t)36 << 20));    // 8MB
  float* semb = (float*)(ws + ((size_t)44 << 20));    // 8MB
  float* tmp  = qb;                                   // alias (disjoint lifetimes)
  int* boundary  = (int*)(ws + ((size_t)52 << 20));
  int* seg_id    = boundary + M_TOT;
  int* seg_start = seg_id + M_TOT;
  int* n_seg     = seg_start + B_*(L_+1);
  float* part_acc  = (float*)(ws + ((size_t)56 << 20));  // 16*4*2*1024*32*4 = 16.78MB
  float* part_lsum = (float*)(ws + ((size_t)73 << 20));  // 0.52MB

  featurize_kernel<<<M_TOT, 64, 0, stream>>>(pts, fs, ft, w_space, b_space, w_time, b_time,
                                             w_fout, b_fout, w_gate, b_gate, zx, boundary);
  scan_kernel<<<B_, 1024, 0, stream>>>(boundary, seg_id, seg_start, n_seg);

  // ---- segment-level encoder (D=64, H=2, FF=128) ----
  for (int l = 0; l < 2; ++l) {
    const float* aw = seg_attn_w + (size_t)l*4*64*64;
    const float* ab = seg_attn_b + (size_t)l*4*64;
    gemm_kernel<64,64,false,false><<<256,256,0,stream>>>(zx, aw + 0*4096, ab + 0,   qb, nullptr);
    gemm_kernel<64,64,false,false><<<256,256,0,stream>>>(zx, aw + 1*4096, ab + 64,  kb, nullptr);
    gemm_kernel<64,64,false,false><<<256,256,0,stream>>>(zx, aw + 2*4096, ab + 128, vb, nullptr);
    seg_attn_kernel<<<(M_TOT*2)/256, 256, 0, stream>>>(qb, kb, vb, seg_id, seg_start, aob);
    gemm_kernel<64,64,false,false><<<256,256,0,stream>>>(aob, aw + 3*4096, ab + 192, tmp, nullptr);
    ln_res_kernel<64,false><<<M_TOT, 64, 0, stream>>>(zx, tmp, seg_ln_g + l*128, seg_ln_b + l*128, nullptr);
    gemm_kernel<128,64,true,false><<<256,256,0,stream>>>(zx, seg_ff1_w + (size_t)l*64*128, seg_ff1_b + l*128, tmp, nullptr);
    gemm_kernel<64,128,false,false><<<256,256,0,stream>>>(tmp, seg_ff2_w + (size_t)l*128*64, seg_ff2_b + l*64, aob, nullptr);
    ln_res_kernel<64,false><<<M_TOT, 64, 0, stream>>>(zx, aob, seg_ln_g + l*128 + 64, seg_ln_b + l*128 + 64, nullptr);
  }

  // ---- pooling + up-projection (gated past n_seg) ----
  pool_kernel<<<M_TOT, 64, 0, stream>>>(zx, seg_start, n_seg, vb);
  gemm_kernel<128,64,false,true><<<256,256,0,stream>>>(vb, up_w, up_b, semb, n_seg);
  hipMemcpyAsync(xg, semb, (size_t)M_TOT*128*4, hipMemcpyDeviceToDevice, stream);

  // ---- global-level encoder (D=128, H=4, FF=256), row-gated on n_seg ----
  for (int l = 0; l < 2; ++l) {
    const float* aw = glb_attn_w + (size_t)l*4*128*128;
    const float* ab = glb_attn_b + (size_t)l*4*128;
    gemm_kernel<128,128,false,true><<<256,256,0,stream>>>(xg, aw + 0*16384, ab + 0,   qb, n_seg);
    gemm_kernel<128,128,false,true><<<256,256,0,stream>>>(xg, aw + 1*16384, ab + 128, kb, n_seg);
    gemm_kernel<128,128,false,true><<<256,256,0,stream>>>(xg, aw + 2*16384, ab + 256, vb, n_seg);
    glb_attn_kernel<<<B_*4*4*2, 128, 0, stream>>>(qb, kb, vb, n_seg, part_acc, part_lsum);
    glb_merge_kernel<<<B_*4*16, 256, 0, stream>>>(part_acc, part_lsum, n_seg, aob);
    gemm_kernel<128,128,false,true><<<256,256,0,stream>>>(aob, aw + 3*16384, ab + 384, tmp, n_seg);
    ln_res_kernel<128,true><<<M_TOT, 128, 0, stream>>>(xg, tmp, glb_ln_g + l*256, glb_ln_b + l*256, n_seg);
    gemm_kernel<256,128,true,true><<<256,256,0,stream>>>(xg, glb_ff1_w + (size_t)l*128*256, glb_ff1_b + l*256, tmp, n_seg);
    gemm_kernel<128,256,false,true><<<256,256,0,stream>>>(tmp, glb_ff2_w + (size_t)l*256*128, glb_ff2_b + l*128, aob, n_seg);
    ln_res_kernel<128,true><<<M_TOT, 128, 0, stream>>>(xg, aob, glb_ln_g + l*256 + 128, glb_ln_b + l*256 + 128, n_seg);
  }

  final_kernel<<<B_, 128, 0, stream>>>(xg, semb, n_seg, fin_w, fin_b, (float*)d_out);
}

// Round 4
// 1269.213 us; speedup vs baseline: 1.2070x; 1.2070x over previous
//
#include <hip/hip_runtime.h>
#include <math.h>

#define B_ 16
#define L_ 1024
#define M_TOT (B_*L_)   // 16384

__device__ __forceinline__ float wave_reduce_sum(float v) {
#pragma unroll
  for (int o = 32; o >= 1; o >>= 1) v += __shfl_xor(v, o, 64);
  return v;
}

__device__ __forceinline__ unsigned short f2bf(float f) {
  union { float f; unsigned u; } v; v.f = f;
  unsigned r = v.u + 0x7FFFu + ((v.u >> 16) & 1u);
  return (unsigned short)(r >> 16);
}
__device__ __forceinline__ float bf2f(unsigned short s) {
  union { unsigned u; float f; } v; v.u = ((unsigned)s) << 16; return v.f;
}

// ---------------- featurize: 4 points per 256-thr block ----------------
__global__ __launch_bounds__(256) void featurize_kernel(
    const float* __restrict__ pts, const float* __restrict__ fs, const float* __restrict__ ft,
    const float* __restrict__ w_space, const float* __restrict__ b_space,
    const float* __restrict__ w_time, const float* __restrict__ b_time,
    const float* __restrict__ w_fout, const float* __restrict__ b_fout,
    const float* __restrict__ w_gate, const float* __restrict__ b_gate,
    float* __restrict__ z, int* __restrict__ boundary)
{
  const int sub = threadIdx.x >> 6;
  const int d   = threadIdx.x & 63;
  const int p   = blockIdx.x * 4 + sub;
  const float TWO_PI = 6.283185307179586f;
  __shared__ float feat[4][32];
  __shared__ float tfeat[4][16];
  __shared__ float g96[4][96];
  const float x = pts[p*3+0], y = pts[p*3+1], t = pts[p*3+2];
  if (d < 16) {
    float sp = (x*fs[d] + y*fs[16+d]) * TWO_PI;
    feat[sub][d]    = sinf(sp);
    feat[sub][16+d] = cosf(sp);
  } else if (d < 24) {
    int r = d - 16;
    float tp = t * ft[r] * TWO_PI;
    tfeat[sub][r]   = sinf(tp);
    tfeat[sub][8+r] = cosf(tp);
  }
  __syncthreads();
  float sf = b_space[d];
#pragma unroll
  for (int k2 = 0; k2 < 32; ++k2) sf = fmaf(feat[sub][k2], w_space[k2*64+d], sf);
  g96[sub][d] = sf;
  if (d < 32) {
    float tf = b_time[d];
#pragma unroll
    for (int k2 = 0; k2 < 16; ++k2) tf = fmaf(tfeat[sub][k2], w_time[k2*32+d], tf);
    g96[sub][64+d] = tf;
  }
  __syncthreads();
  float zv = b_fout[d];
#pragma unroll
  for (int k2 = 0; k2 < 96; ++k2) zv = fmaf(g96[sub][k2], w_fout[k2*64+d], zv);
  z[(size_t)p*64+d] = zv;
  float gv = wave_reduce_sum(zv * w_gate[d]);
  if (d == 0) {
    float logit = gv + b_gate[0];
    float gate = 1.0f / (1.0f + expf(-logit));
    int bnd = (gate > 0.5f) ? 1 : 0;
    if ((p & (L_-1)) == 0) bnd = 1;
    boundary[p] = bnd;
  }
}

// ---------------- scan: seg_id, seg_start, n_seg ----------------
__global__ __launch_bounds__(1024) void scan_kernel(const int* __restrict__ boundary,
    int* __restrict__ seg_id, int* __restrict__ seg_start, int* __restrict__ n_seg)
{
  __shared__ int sc[1024];
  const int b = blockIdx.x, l = threadIdx.x;
  const int v = boundary[b*L_ + l];
  sc[l] = v;
  __syncthreads();
  for (int off = 1; off < 1024; off <<= 1) {
    int add = (l >= off) ? sc[l - off] : 0;
    __syncthreads();
    sc[l] += add;
    __syncthreads();
  }
  const int sid = sc[l] - 1;
  seg_id[b*L_ + l] = sid;
  if (v) seg_start[b*(L_+1) + sid] = l;
  if (l == L_-1) {
    n_seg[b] = sid + 1;
    seg_start[b*(L_+1) + sid + 1] = L_;
  }
}

// ---------------- generic GEMM: C = act(A[M,K] @ W[K,N] + bias) ----------------
template<int N, int K, bool RELU, bool GATED>
__global__ __launch_bounds__(256) void gemm_kernel(
    const float* __restrict__ A, const float* __restrict__ W,
    const float* __restrict__ bias, float* __restrict__ C,
    const int* __restrict__ nseg)
{
  constexpr int BM = 64, BK = 32;
  constexpr int TN = N / 16;
  const int row0 = blockIdx.x * BM;
  if (GATED) {
    const int b = row0 >> 10, i0 = row0 & (L_-1);
    if (i0 >= nseg[b]) return;
  }
  __shared__ float As[BM][BK + 4];
  const int tid = threadIdx.x;
  const int ty = tid >> 4, tx = tid & 15;
  float acc[4][TN];
#pragma unroll
  for (int i = 0; i < 4; ++i)
#pragma unroll
    for (int j = 0; j < TN; ++j) acc[i][j] = 0.f;
  const int lr = tid >> 2;
  const int lc = (tid & 3) * 8;
  for (int k0 = 0; k0 < K; k0 += BK) {
    const float4* src = reinterpret_cast<const float4*>(A + (size_t)(row0 + lr)*K + k0 + lc);
    float4 a0 = src[0], a1 = src[1];
    *reinterpret_cast<float4*>(&As[lr][lc])   = a0;
    *reinterpret_cast<float4*>(&As[lr][lc+4]) = a1;
    __syncthreads();
#pragma unroll 8
    for (int kk = 0; kk < BK; ++kk) {
      float a[4];
#pragma unroll
      for (int i = 0; i < 4; ++i) a[i] = As[ty*4+i][kk];
      const float4* wr = reinterpret_cast<const float4*>(W + (size_t)(k0+kk)*N + tx*TN);
      float w[TN];
#pragma unroll
      for (int j4 = 0; j4 < TN/4; ++j4) {
        float4 wv = wr[j4];
        w[j4*4+0]=wv.x; w[j4*4+1]=wv.y; w[j4*4+2]=wv.z; w[j4*4+3]=wv.w;
      }
#pragma unroll
      for (int i = 0; i < 4; ++i)
#pragma unroll
        for (int j = 0; j < TN; ++j)
          acc[i][j] = fmaf(a[i], w[j], acc[i][j]);
    }
    __syncthreads();
  }
#pragma unroll
  for (int i = 0; i < 4; ++i) {
    const int row = row0 + ty*4 + i;
#pragma unroll
    for (int j = 0; j < TN; ++j) {
      const int col = tx*TN + j;
      float v2 = acc[i][j] + bias[col];
      if (RELU) v2 = fmaxf(v2, 0.f);
      C[(size_t)row*N + col] = v2;
    }
  }
}

// ---------------- fused QKV GEMM: C[row][p*PN+col] = A@Wp + bp, p=0..2 ---------
// W: 3 parts of [K][PN] contiguous (part stride K*PN); bias: 3*PN contiguous.
template<int PN, int K, bool GATED>
__global__ __launch_bounds__(256) void gemm_qkv_kernel(
    const float* __restrict__ A, const float* __restrict__ W,
    const float* __restrict__ bias, float* __restrict__ C,
    const int* __restrict__ nseg)
{
  constexpr int BM = 64, BK = 32;
  constexpr int TN = PN / 16;
  constexpr int NO = 3 * PN;
  const int row0 = blockIdx.x * BM;
  if (GATED) {
    const int b = row0 >> 10, i0 = row0 & (L_-1);
    if (i0 >= nseg[b]) return;
  }
  __shared__ float As[BM][BK + 4];
  const int tid = threadIdx.x;
  const int ty = tid >> 4, tx = tid & 15;
  float acc[4][3][TN];
#pragma unroll
  for (int i = 0; i < 4; ++i)
#pragma unroll
    for (int p = 0; p < 3; ++p)
#pragma unroll
      for (int j = 0; j < TN; ++j) acc[i][p][j] = 0.f;
  const int lr = tid >> 2;
  const int lc = (tid & 3) * 8;
  for (int k0 = 0; k0 < K; k0 += BK) {
    const float4* src = reinterpret_cast<const float4*>(A + (size_t)(row0 + lr)*K + k0 + lc);
    float4 a0 = src[0], a1 = src[1];
    *reinterpret_cast<float4*>(&As[lr][lc])   = a0;
    *reinterpret_cast<float4*>(&As[lr][lc+4]) = a1;
    __syncthreads();
#pragma unroll 4
    for (int kk = 0; kk < BK; ++kk) {
      float a[4];
#pragma unroll
      for (int i = 0; i < 4; ++i) a[i] = As[ty*4+i][kk];
      float w[3][TN];
#pragma unroll
      for (int p = 0; p < 3; ++p) {
        const float4* wr = reinterpret_cast<const float4*>(
            W + (size_t)p*K*PN + (size_t)(k0+kk)*PN + tx*TN);
#pragma unroll
        for (int j4 = 0; j4 < TN/4; ++j4) {
          float4 wv = wr[j4];
          w[p][j4*4+0]=wv.x; w[p][j4*4+1]=wv.y; w[p][j4*4+2]=wv.z; w[p][j4*4+3]=wv.w;
        }
      }
#pragma unroll
      for (int i = 0; i < 4; ++i)
#pragma unroll
        for (int p = 0; p < 3; ++p)
#pragma unroll
          for (int j = 0; j < TN; ++j)
            acc[i][p][j] = fmaf(a[i], w[p][j], acc[i][p][j]);
    }
    __syncthreads();
  }
#pragma unroll
  for (int i = 0; i < 4; ++i) {
    const int row = row0 + ty*4 + i;
#pragma unroll
    for (int p = 0; p < 3; ++p)
#pragma unroll
      for (int j = 0; j < TN; ++j) {
        const int col = tx*TN + j;
        C[(size_t)row*NO + p*PN + col] = acc[i][p][j] + bias[p*PN + col];
      }
  }
}

// ---------------- segment attention (block-diagonal, exact; fixed-shift) -------
// qkv packed: [row][3][64]; q at +0, k at +64, v at +128 (h*32 within part)
__global__ __launch_bounds__(256) void seg_attn_kernel(
    const float* __restrict__ qkv,
    const int* __restrict__ seg_id, const int* __restrict__ seg_start,
    float* __restrict__ ao)
{
  const int idx = blockIdx.x * 256 + threadIdx.x;  // ((b*L + pt)*2 + h)
  const int h  = idx & 1;
  const int pt = (idx >> 1) & (L_-1);
  const int b  = idx >> 11;
  const float scale = 0.17677669529663687f; // 1/sqrt(32)
  float qv[32];
  {
    const float4* qp = reinterpret_cast<const float4*>(qkv + (size_t)(b*L_+pt)*192 + h*32);
#pragma unroll
    for (int j4 = 0; j4 < 8; ++j4) {
      float4 t4 = qp[j4];
      qv[j4*4+0]=t4.x*scale; qv[j4*4+1]=t4.y*scale; qv[j4*4+2]=t4.z*scale; qv[j4*4+3]=t4.w*scale;
    }
  }
  const int s  = seg_id[b*L_ + pt];
  const int j0 = seg_start[b*(L_+1) + s];
  const int j1 = seg_start[b*(L_+1) + s + 1];
  float lsum = 0.f;
  float acc[32];
#pragma unroll
  for (int d = 0; d < 32; ++d) acc[d] = 0.f;
  for (int j = j0; j < j1; ++j) {
    const float* base = qkv + (size_t)(b*L_ + j)*192 + h*32;
    const float4* kp = reinterpret_cast<const float4*>(base + 64);
    float dot = 0.f;
#pragma unroll
    for (int j4 = 0; j4 < 8; ++j4) {
      float4 t4 = kp[j4];
      dot = fmaf(qv[j4*4+0], t4.x, dot);
      dot = fmaf(qv[j4*4+1], t4.y, dot);
      dot = fmaf(qv[j4*4+2], t4.z, dot);
      dot = fmaf(qv[j4*4+3], t4.w, dot);
    }
    const float p = __expf(fminf(dot, 30.f));
    lsum += p;
    const float4* vp = reinterpret_cast<const float4*>(base + 128);
#pragma unroll
    for (int j4 = 0; j4 < 8; ++j4) {
      float4 t4 = vp[j4];
      acc[j4*4+0] = fmaf(p, t4.x, acc[j4*4+0]);
      acc[j4*4+1] = fmaf(p, t4.y, acc[j4*4+1]);
      acc[j4*4+2] = fmaf(p, t4.z, acc[j4*4+2]);
      acc[j4*4+3] = fmaf(p, t4.w, acc[j4*4+3]);
    }
  }
  const float inv = 1.0f / lsum;
  float* op = ao + (size_t)(b*L_+pt)*64 + h*32;
#pragma unroll
  for (int d = 0; d < 32; ++d) op[d] = acc[d] * inv;
}

// ---------------- global attention v4: 256 thr, NQ=2, kt=8 key-split -----------
// grid: blockIdx.x = (((b*4 + h)*2 + qt)*8 + kt)
// xqkv packed: [row][3][128]; q +0, k +128, v +256
__global__ __launch_bounds__(256) void glb_attn_kernel(
    const float* __restrict__ xqkv, const int* __restrict__ n_seg,
    unsigned short* __restrict__ part_acc, float* __restrict__ part_lsum)
{
  const int kt = blockIdx.x & 7;
  const int qt = (blockIdx.x >> 3) & 1;
  const int h  = (blockIdx.x >> 4) & 3;
  const int b  = blockIdx.x >> 6;
  const int ns = n_seg[b];
  if (qt*512 >= ns) return;
  const int kchunk = (ns + 7) >> 3;
  const int kbeg = kt * kchunk;
  const int kend = min(ns, kbeg + kchunk);
  if (kbeg >= kend) return;

  const int tid = (int)threadIdx.x;
  const int q0 = qt*512 + tid;
  const int q1 = q0 + 256;
  const bool a0 = q0 < ns, a1 = q1 < ns;
  const float scale = 0.17677669529663687f;

  __shared__ float Ks[64][36];
  __shared__ float Vs[64][36];

  float qv0[32], qv1[32];
#pragma unroll
  for (int d = 0; d < 32; ++d) { qv0[d] = 0.f; qv1[d] = 0.f; }
  if (a0) {
    const float4* qp = reinterpret_cast<const float4*>(xqkv + (size_t)(b*L_+q0)*384 + h*32);
#pragma unroll
    for (int j4 = 0; j4 < 8; ++j4) {
      float4 t4 = qp[j4];
      qv0[j4*4+0]=t4.x*scale; qv0[j4*4+1]=t4.y*scale; qv0[j4*4+2]=t4.z*scale; qv0[j4*4+3]=t4.w*scale;
    }
  }
  if (a1) {
    const float4* qp = reinterpret_cast<const float4*>(xqkv + (size_t)(b*L_+q1)*384 + h*32);
#pragma unroll
    for (int j4 = 0; j4 < 8; ++j4) {
      float4 t4 = qp[j4];
      qv1[j4*4+0]=t4.x*scale; qv1[j4*4+1]=t4.y*scale; qv1[j4*4+2]=t4.z*scale; qv1[j4*4+3]=t4.w*scale;
    }
  }

  float l0 = 0.f, l1 = 0.f;
  float acc0[32], acc1[32];
#pragma unroll
  for (int d = 0; d < 32; ++d) { acc0[d] = 0.f; acc1[d] = 0.f; }

  for (int j0 = kbeg; j0 < kend; j0 += 64) {
    const int nj = min(64, kend - j0);
    __syncthreads();
    {
      const int jr = tid >> 2;
      const int c  = (tid & 3) * 8;
      if (jr < nj) {
        const float* base = xqkv + (size_t)(b*L_ + j0 + jr)*384 + h*32 + c;
        *reinterpret_cast<float4*>(&Ks[jr][c])   = *reinterpret_cast<const float4*>(base + 128);
        *reinterpret_cast<float4*>(&Ks[jr][c+4]) = *reinterpret_cast<const float4*>(base + 132);
        *reinterpret_cast<float4*>(&Vs[jr][c])   = *reinterpret_cast<const float4*>(base + 256);
        *reinterpret_cast<float4*>(&Vs[jr][c+4]) = *reinterpret_cast<const float4*>(base + 260);
      }
    }
    __syncthreads();
#pragma unroll 2
    for (int j = 0; j < nj; ++j) {
      const float4* kr = reinterpret_cast<const float4*>(&Ks[j][0]);
      float s0a=0.f,s0b=0.f,s1a=0.f,s1b=0.f;
#pragma unroll
      for (int j4 = 0; j4 < 8; ++j4) {
        float4 t4 = kr[j4];
        s0a = fmaf(qv0[j4*4+0], t4.x, s0a);
        s0b = fmaf(qv0[j4*4+1], t4.y, s0b);
        s0a = fmaf(qv0[j4*4+2], t4.z, s0a);
        s0b = fmaf(qv0[j4*4+3], t4.w, s0b);
        s1a = fmaf(qv1[j4*4+0], t4.x, s1a);
        s1b = fmaf(qv1[j4*4+1], t4.y, s1b);
        s1a = fmaf(qv1[j4*4+2], t4.z, s1a);
        s1b = fmaf(qv1[j4*4+3], t4.w, s1b);
      }
      const float p0 = __expf(fminf(s0a + s0b, 30.f));
      const float p1 = __expf(fminf(s1a + s1b, 30.f));
      l0 += p0; l1 += p1;
      const float4* vr = reinterpret_cast<const float4*>(&Vs[j][0]);
#pragma unroll
      for (int j4 = 0; j4 < 8; ++j4) {
        float4 t4 = vr[j4];
        acc0[j4*4+0] = fmaf(p0, t4.x, acc0[j4*4+0]);
        acc0[j4*4+1] = fmaf(p0, t4.y, acc0[j4*4+1]);
        acc0[j4*4+2] = fmaf(p0, t4.z, acc0[j4*4+2]);
        acc0[j4*4+3] = fmaf(p0, t4.w, acc0[j4*4+3]);
        acc1[j4*4+0] = fmaf(p1, t4.x, acc1[j4*4+0]);
        acc1[j4*4+1] = fmaf(p1, t4.y, acc1[j4*4+1]);
        acc1[j4*4+2] = fmaf(p1, t4.z, acc1[j4*4+2]);
        acc1[j4*4+3] = fmaf(p1, t4.w, acc1[j4*4+3]);
      }
    }
  }
  const int pslot = ((b*4 + h)*8 + kt)*1024;
  if (a0) {
    part_lsum[pslot + q0] = l0;
    unsigned int pw[16];
#pragma unroll
    for (int i = 0; i < 16; ++i)
      pw[i] = (unsigned)f2bf(acc0[2*i]) | ((unsigned)f2bf(acc0[2*i+1]) << 16);
    uint4* pa = reinterpret_cast<uint4*>(part_acc + (size_t)(pslot + q0)*32);
#pragma unroll
    for (int i = 0; i < 4; ++i) {
      uint4 u; u.x = pw[i*4+0]; u.y = pw[i*4+1]; u.z = pw[i*4+2]; u.w = pw[i*4+3];
      pa[i] = u;
    }
  }
  if (a1) {
    part_lsum[pslot + q1] = l1;
    unsigned int pw[16];
#pragma unroll
    for (int i = 0; i < 16; ++i)
      pw[i] = (unsigned)f2bf(acc1[2*i]) | ((unsigned)f2bf(acc1[2*i+1]) << 16);
    uint4* pa = reinterpret_cast<uint4*>(part_acc + (size_t)(pslot + q1)*32);
#pragma unroll
    for (int i = 0; i < 4; ++i) {
      uint4 u; u.x = pw[i*4+0]; u.y = pw[i*4+1]; u.z = pw[i*4+2]; u.w = pw[i*4+3];
      pa[i] = u;
    }
  }
}

// ---------------- merge 8 kt partials -> normalized attention output -----------
// grid: blockIdx.x = ((b*4 + h)*16 + qt64); block = 256 (64 q x 4 d-groups of 8)
__global__ __launch_bounds__(256) void glb_merge_kernel(
    const unsigned short* __restrict__ part_acc, const float* __restrict__ part_lsum,
    const int* __restrict__ n_seg, float* __restrict__ ao)
{
  const int qt = blockIdx.x & 15;
  const int h  = (blockIdx.x >> 4) & 3;
  const int b  = blockIdx.x >> 6;
  const int ns = n_seg[b];
  if (qt*64 >= ns) return;
  const int q  = qt*64 + ((int)threadIdx.x >> 2);
  if (q >= ns) return;
  const int dg = ((int)threadIdx.x & 3) * 8;
  const int kchunk = (ns + 7) >> 3;
  float ls = 0.f;
  float a[8];
#pragma unroll
  for (int i = 0; i < 8; ++i) a[i] = 0.f;
#pragma unroll
  for (int kt = 0; kt < 8; ++kt) {
    if (kt * kchunk < ns) {
      const int base = ((b*4 + h)*8 + kt)*1024 + q;
      ls += part_lsum[base];
      const uint4 pv = *reinterpret_cast<const uint4*>(part_acc + (size_t)base*32 + dg);
      a[0] += bf2f((unsigned short)(pv.x & 0xFFFF)); a[1] += bf2f((unsigned short)(pv.x >> 16));
      a[2] += bf2f((unsigned short)(pv.y & 0xFFFF)); a[3] += bf2f((unsigned short)(pv.y >> 16));
      a[4] += bf2f((unsigned short)(pv.z & 0xFFFF)); a[5] += bf2f((unsigned short)(pv.z >> 16));
      a[6] += bf2f((unsigned short)(pv.w & 0xFFFF)); a[7] += bf2f((unsigned short)(pv.w >> 16));
    }
  }
  const float inv = 1.0f / ls;
  float* op = ao + (size_t)(b*L_ + q)*128 + h*32 + dg;
  reinterpret_cast<float4*>(op)[0] = make_float4(a[0]*inv, a[1]*inv, a[2]*inv, a[3]*inv);
  reinterpret_cast<float4*>(op)[1] = make_float4(a[4]*inv, a[5]*inv, a[6]*inv, a[7]*inv);
}

// ---------------- LN(x+r) D=64: 4 rows per 256-thr block (1 wave = 1 row) ------
__global__ __launch_bounds__(256) void ln64_kernel(
    float* __restrict__ x, const float* __restrict__ r,
    const float* __restrict__ gam, const float* __restrict__ bet)
{
  const int row = blockIdx.x*4 + ((int)threadIdx.x >> 6);
  const int d = (int)threadIdx.x & 63;
  float val = x[(size_t)row*64 + d] + r[(size_t)row*64 + d];
  float s = wave_reduce_sum(val);
  const float mean = s * (1.0f/64.0f);
  const float dv = val - mean;
  float s2 = wave_reduce_sum(dv*dv);
  x[(size_t)row*64 + d] = dv * rsqrtf(s2*(1.0f/64.0f) + 1e-5f) * gam[d] + bet[d];
}

// ---------------- LN(x+r) D=128 gated: 2 rows per 256-thr block ----------------
__global__ __launch_bounds__(256) void ln128_kernel(
    float* __restrict__ x, const float* __restrict__ r,
    const float* __restrict__ gam, const float* __restrict__ bet,
    const int* __restrict__ nseg)
{
  const int row0 = blockIdx.x*2;
  const int b = row0 >> 10;
  if ((row0 & (L_-1)) >= nseg[b]) return;   // both rows invalid -> uniform exit
  const int sub = (int)threadIdx.x >> 7;    // 0..1
  const int d   = (int)threadIdx.x & 127;
  const int row = row0 + sub;
  const bool valid = (row & (L_-1)) < nseg[b];
  __shared__ float red[2][4];
  float val = 0.f;
  if (valid) val = x[(size_t)row*128 + d] + r[(size_t)row*128 + d];
  float s = wave_reduce_sum(val);
  if ((d & 63) == 0) red[sub][d >> 6] = s;
  __syncthreads();
  s = red[sub][0] + red[sub][1];
  const float mean = s * (1.0f/128.0f);
  const float dv = val - mean;
  float s2 = wave_reduce_sum(dv*dv);
  if ((d & 63) == 0) red[sub][2 + (d >> 6)] = s2;
  __syncthreads();
  s2 = red[sub][2] + red[sub][3];
  if (valid)
    x[(size_t)row*128 + d] = dv * rsqrtf(s2*(1.0f/128.0f) + 1e-5f) * gam[d] + bet[d];
}

// ---------------- segment mean pooling: 4 segs per 256-thr block ---------------
__global__ __launch_bounds__(256) void pool_kernel(
    const float* __restrict__ h, const int* __restrict__ seg_start,
    const int* __restrict__ n_seg, float* __restrict__ mean)
{
  const int gs = blockIdx.x*4 + ((int)threadIdx.x >> 6);
  const int b = gs >> 10, s = gs & (L_-1);
  const int d = (int)threadIdx.x & 63;
  if (s >= n_seg[b]) return;
  const int j0 = seg_start[b*(L_+1)+s], j1 = seg_start[b*(L_+1)+s+1];
  float acc = 0.f;
  for (int j = j0; j < j1; ++j) acc += h[(size_t)(b*L_+j)*64 + d];
  mean[(size_t)gs*64 + d] = acc / (float)(j1 - j0);
}

// ---------------- save row0 of xg (post-up-projection) for ns==1 path ----------
__global__ __launch_bounds__(128) void row0_kernel(
    const float* __restrict__ xg, float* __restrict__ semb0)
{
  semb0[blockIdx.x*128 + threadIdx.x] = xg[(size_t)blockIdx.x*L_*128 + threadIdx.x];
}

// ---------------- final: pooled @ fin_w + fin_b ----------------
__global__ __launch_bounds__(128) void final_kernel(
    const float* __restrict__ g, const float* __restrict__ semb0,
    const int* __restrict__ n_seg, const float* __restrict__ fin_w,
    const float* __restrict__ fin_b, float* __restrict__ out)
{
  const int b = blockIdx.x, d = threadIdx.x;
  const int ns = n_seg[b];
  __shared__ float pl[128];
  float pooled;
  if (ns == 1) pooled = semb0[b*128 + d];
  else {
    float acc = 0.f;
    for (int i = 0; i < ns; ++i) acc += g[(size_t)(b*L_+i)*128 + d];
    pooled = acc / (float)ns;
  }
  pl[d] = pooled;
  __syncthreads();
  float o = fin_b[d];
#pragma unroll 8
  for (int k2 = 0; k2 < 128; ++k2) o = fmaf(pl[k2], fin_w[k2*128+d], o);
  out[b*128+d] = o;
}

extern "C" void kernel_launch(void* const* d_in, const int* in_sizes, int n_in,
                              void* d_out, int out_size, void* d_ws, size_t ws_size,
                              hipStream_t stream) {
  const float* pts     = (const float*)d_in[0];
  const float* fs      = (const float*)d_in[1];
  const float* ft      = (const float*)d_in[2];
  const float* w_space = (const float*)d_in[3];
  const float* b_space = (const float*)d_in[4];
  const float* w_time  = (const float*)d_in[5];
  const float* b_time  = (const float*)d_in[6];
  const float* w_fout  = (const float*)d_in[7];
  const float* b_fout  = (const float*)d_in[8];
  const float* w_gate  = (const float*)d_in[9];
  const float* b_gate  = (const float*)d_in[10];
  const float* seg_attn_w = (const float*)d_in[11];
  const float* seg_attn_b = (const float*)d_in[12];
  const float* seg_ln_g   = (const float*)d_in[13];
  const float* seg_ln_b   = (const float*)d_in[14];
  const float* seg_ff1_w  = (const float*)d_in[15];
  const float* seg_ff1_b  = (const float*)d_in[16];
  const float* seg_ff2_w  = (const float*)d_in[17];
  const float* seg_ff2_b  = (const float*)d_in[18];
  const float* glb_attn_w = (const float*)d_in[19];
  const float* glb_attn_b = (const float*)d_in[20];
  const float* glb_ln_g   = (const float*)d_in[21];
  const float* glb_ln_b   = (const float*)d_in[22];
  const float* glb_ff1_w  = (const float*)d_in[23];
  const float* glb_ff1_b  = (const float*)d_in[24];
  const float* glb_ff2_w  = (const float*)d_in[25];
  const float* glb_ff2_b  = (const float*)d_in[26];
  const float* up_w    = (const float*)d_in[27];
  const float* up_b    = (const float*)d_in[28];
  const float* fin_w   = (const float*)d_in[29];
  const float* fin_b   = (const float*)d_in[30];

  // workspace layout (MB offsets):
  // 0-4 zx | 4-30 qkv/tmp | 30-38 aob(+pooled) | 38-46 xg | 46-47 ints
  // 47-48 semb0 | 48-50 part_lsum | 50-84 part_acc(bf16)
  char* ws = (char*)d_ws;
  float* zx   = (float*)(ws);
  float* qkv  = (float*)(ws + ((size_t)4  << 20));  // seg: 12.6MB, glb: 25.2MB
  float* tmp  = qkv;                                // alias (disjoint lifetimes)
  float* aob  = (float*)(ws + ((size_t)30 << 20));
  float* xg   = (float*)(ws + ((size_t)38 << 20));
  int* boundary  = (int*)(ws + ((size_t)46 << 20));
  int* seg_id    = boundary + M_TOT;
  int* seg_start = seg_id + M_TOT;
  int* n_seg     = seg_start + B_*(L_+1);
  float* semb0     = (float*)(ws + ((size_t)47 << 20));
  float* part_lsum = (float*)(ws + ((size_t)48 << 20));
  unsigned short* part_acc = (unsigned short*)(ws + ((size_t)50 << 20));

  featurize_kernel<<<M_TOT/4, 256, 0, stream>>>(pts, fs, ft, w_space, b_space, w_time, b_time,
                                                w_fout, b_fout, w_gate, b_gate, zx, boundary);
  scan_kernel<<<B_, 1024, 0, stream>>>(boundary, seg_id, seg_start, n_seg);

  // ---- segment-level encoder (D=64, H=2, FF=128) ----
  for (int l = 0; l < 2; ++l) {
    const float* aw = seg_attn_w + (size_t)l*4*64*64;
    const float* ab = seg_attn_b + (size_t)l*4*64;
    gemm_qkv_kernel<64,64,false><<<256,256,0,stream>>>(zx, aw, ab, qkv, nullptr);
    seg_attn_kernel<<<(M_TOT*2)/256, 256, 0, stream>>>(qkv, seg_id, seg_start, aob);
    gemm_kernel<64,64,false,false><<<256,256,0,stream>>>(aob, aw + 3*4096, ab + 192, tmp, nullptr);
    ln64_kernel<<<M_TOT/4, 256, 0, stream>>>(zx, tmp, seg_ln_g + l*128, seg_ln_b + l*128);
    gemm_kernel<128,64,true,false><<<256,256,0,stream>>>(zx, seg_ff1_w + (size_t)l*64*128, seg_ff1_b + l*128, tmp, nullptr);
    gemm_kernel<64,128,false,false><<<256,256,0,stream>>>(tmp, seg_ff2_w + (size_t)l*128*64, seg_ff2_b + l*64, aob, nullptr);
    ln64_kernel<<<M_TOT/4, 256, 0, stream>>>(zx, aob, seg_ln_g + l*128 + 64, seg_ln_b + l*128 + 64);
  }

  // ---- pooling + up-projection (gated past n_seg) ----
  pool_kernel<<<M_TOT/4, 256, 0, stream>>>(zx, seg_start, n_seg, aob);
  gemm_kernel<128,64,false,true><<<256,256,0,stream>>>(aob, up_w, up_b, xg, n_seg);
  row0_kernel<<<B_, 128, 0, stream>>>(xg, semb0);

  // ---- global-level encoder (D=128, H=4, FF=256), row-gated on n_seg ----
  for (int l = 0; l < 2; ++l) {
    const float* aw = glb_attn_w + (size_t)l*4*128*128;
    const float* ab = glb_attn_b + (size_t)l*4*128;
    gemm_qkv_kernel<128,128,true><<<256,256,0,stream>>>(xg, aw, ab, qkv, n_seg);
    glb_attn_kernel<<<B_*4*2*8, 256, 0, stream>>>(qkv, n_seg, part_acc, part_lsum);
    glb_merge_kernel<<<B_*4*16, 256, 0, stream>>>(part_acc, part_lsum, n_seg, aob);
    gemm_kernel<128,128,false,true><<<256,256,0,stream>>>(aob, aw + 3*16384, ab + 384, tmp, n_seg);
    ln128_kernel<<<M_TOT/2, 256, 0, stream>>>(xg, tmp, glb_ln_g + l*256, glb_ln_b + l*256, n_seg);
    gemm_kernel<256,128,true,true><<<256,256,0,stream>>>(xg, glb_ff1_w + (size_t)l*128*256, glb_ff1_b + l*256, tmp, n_seg);
    gemm_kernel<128,256,false,true><<<256,256,0,stream>>>(tmp, glb_ff2_w + (size_t)l*256*128, glb_ff2_b + l*128, aob, n_seg);
    ln128_kernel<<<M_TOT/2, 256, 0, stream>>>(xg, aob, glb_ln_g + l*256 + 128, glb_ln_b + l*256 + 128, n_seg);
  }

  final_kernel<<<B_, 128, 0, stream>>>(xg, semb0, n_seg, fin_w, fin_b, (float*)d_out);
}